// Round 3
// baseline (121.019 us; speedup 1.0000x reference)
//
#include <hip/hip_runtime.h>

#define BD 128   // D
#define SL 512   // L
#define NB 4     // B

__device__ __forceinline__ float rcp_fast(float x) { return __builtin_amdgcn_rcpf(x); }

// K1: qu = inp@Wu.T, kw = inp@Ww.T with in-block LDS transpose staging of W.
// Grid 512 x 256; block handles 4 rows; t<128 -> qu col o, t>=128 -> kw col o.
// Writes Equ=exp(2qu) TRANSPOSED (b,d,l) and Ekw=exp(2kw) (b,l,d).
__global__ __launch_bounds__(256, 2) void k_qk(const float* __restrict__ inp,
                                               const float* __restrict__ Wu,
                                               const float* __restrict__ Ww,
                                               float* __restrict__ Equ,
                                               float* __restrict__ Ekw) {
    __shared__ float sx[4][BD];            // 4 input rows
    __shared__ float swT[2][32][BD + 1];   // [mat][kk][o], transposed W chunk, padded

    const int t  = threadIdx.x;
    const int r0 = blockIdx.x * 4;         // global row = b*SL + l
    const int b  = r0 >> 9;
    const int l0 = r0 & (SL - 1);

    #pragma unroll
    for (int h = 0; h < 2; ++h) {
        int idx = h * 256 + t;             // 0..511
        sx[idx >> 7][idx & 127] = inp[(size_t)(r0 + (idx >> 7)) * BD + (idx & 127)];
    }

    const int m = t >> 7, o = t & 127;
    float acc[4] = {0.f, 0.f, 0.f, 0.f};

    for (int k0 = 0; k0 < BD; k0 += 32) {
        __syncthreads();                   // protects sx (first iter) + swT reuse
        #pragma unroll
        for (int i = 0; i < 32; ++i) {
            int idx = i * 256 + t;         // 0..8191
            int mm  = idx >> 12;
            int rem = idx & 4095;
            int oo  = rem >> 5, kk = rem & 31;
            swT[mm][kk][oo] = (mm ? Ww : Wu)[oo * BD + k0 + kk];
        }
        __syncthreads();
        #pragma unroll
        for (int kk = 0; kk < 32; kk += 4) {
            float w0 = swT[m][kk + 0][o];
            float w1 = swT[m][kk + 1][o];
            float w2 = swT[m][kk + 2][o];
            float w3 = swT[m][kk + 3][o];
            #pragma unroll
            for (int rr = 0; rr < 4; ++rr) {
                float4 x = *(const float4*)&sx[rr][k0 + kk];
                acc[rr] = fmaf(x.x, w0, acc[rr]);
                acc[rr] = fmaf(x.y, w1, acc[rr]);
                acc[rr] = fmaf(x.z, w2, acc[rr]);
                acc[rr] = fmaf(x.w, w3, acc[rr]);
            }
        }
    }

    if (m == 0) {
        #pragma unroll
        for (int rr = 0; rr < 4; ++rr)     // transposed scatter (small: 1MB total)
            Equ[((size_t)b * BD + o) * SL + l0 + rr] = __expf(2.f * acc[rr]);
    } else {
        #pragma unroll
        for (int rr = 0; rr < 4; ++rr)     // coalesced
            Ekw[(size_t)(r0 + rr) * BD + o] = __expf(2.f * acc[rr]);
    }
}

// K2: block = (b, 8 query rows), 512 threads; thread t owns key column j=t.
// Phase 1: a[i] = sum_d wv/(1+Equ[d][j]*Ekw[i][d]); score = C-2a (C cancels).
// Phase 2: softmax over j. Phase 3: out = attn @ inp, thread = (i-group, d-pair).
// Grid 256 blocks, batch-major order -> per-batch 512 KB working set stays L2-hot.
__global__ __launch_bounds__(512, 2) void k_attn(const float* __restrict__ inp,
                                                 const float* __restrict__ Wv,
                                                 const float* __restrict__ Equ,
                                                 const float* __restrict__ Ekw,
                                                 float* __restrict__ out,
                                                 float* __restrict__ attn) {
    __shared__ float s_ek[BD][8];          // [d][i] Ekw for the 8 i-rows
    __shared__ float s_wv[BD];
    __shared__ float s_p[8][SL];           // normalized attn weights
    __shared__ float s_red[8][8];          // [i][wave] reductions

    const int t  = threadIdx.x;            // = j in phase 1
    const int b  = blockIdx.x >> 6;        // blocks 0..63 -> batch 0, etc.
    const int i0 = (blockIdx.x & 63) * 8;

    #pragma unroll
    for (int h = 0; h < 2; ++h) {
        int id = h * 512 + t;              // 0..1023
        int i = id >> 7, d = id & 127;
        s_ek[d][i] = Ekw[((size_t)b * SL + i0 + i) * BD + d];  // coalesced read
    }
    if (t < BD) s_wv[t] = Wv[t];
    __syncthreads();

    // Phase 1: 8 independent rcp chains per thread.
    const float* equ = Equ + (size_t)b * BD * SL;   // [d][l]
    float a[8];
    #pragma unroll
    for (int i = 0; i < 8; ++i) a[i] = 0.f;

    #pragma unroll 4
    for (int d = 0; d < BD; ++d) {
        float  q  = equ[d * SL + t];                // coalesced 256B/wave
        float4 e0 = *(const float4*)&s_ek[d][0];    // b128 broadcast
        float4 e1 = *(const float4*)&s_ek[d][4];
        float  w  = s_wv[d];
        a[0] = fmaf(w, rcp_fast(fmaf(q, e0.x, 1.f)), a[0]);
        a[1] = fmaf(w, rcp_fast(fmaf(q, e0.y, 1.f)), a[1]);
        a[2] = fmaf(w, rcp_fast(fmaf(q, e0.z, 1.f)), a[2]);
        a[3] = fmaf(w, rcp_fast(fmaf(q, e0.w, 1.f)), a[3]);
        a[4] = fmaf(w, rcp_fast(fmaf(q, e1.x, 1.f)), a[4]);
        a[5] = fmaf(w, rcp_fast(fmaf(q, e1.y, 1.f)), a[5]);
        a[6] = fmaf(w, rcp_fast(fmaf(q, e1.z, 1.f)), a[6]);
        a[7] = fmaf(w, rcp_fast(fmaf(q, e1.w, 1.f)), a[7]);
    }

    // Phase 2: softmax over j of score = -2a -> reduce MIN of a per row.
    const int wid = t >> 6;
    float mn[8];
    #pragma unroll
    for (int i = 0; i < 8; ++i) mn[i] = a[i];
    #pragma unroll
    for (int off = 32; off > 0; off >>= 1) {
        #pragma unroll
        for (int i = 0; i < 8; ++i) mn[i] = fminf(mn[i], __shfl_xor(mn[i], off, 64));
    }
    if ((t & 63) == 0) {
        #pragma unroll
        for (int i = 0; i < 8; ++i) s_red[i][wid] = mn[i];
    }
    __syncthreads();
    #pragma unroll
    for (int i = 0; i < 8; ++i) {
        float4 r0 = *(const float4*)&s_red[i][0];
        float4 r1 = *(const float4*)&s_red[i][4];
        mn[i] = fminf(fminf(fminf(r0.x, r0.y), fminf(r0.z, r0.w)),
                      fminf(fminf(r1.x, r1.y), fminf(r1.z, r1.w)));
    }

    float p[8], sm[8];
    #pragma unroll
    for (int i = 0; i < 8; ++i) { p[i] = __expf(-2.f * (a[i] - mn[i])); sm[i] = p[i]; }
    #pragma unroll
    for (int off = 32; off > 0; off >>= 1) {
        #pragma unroll
        for (int i = 0; i < 8; ++i) sm[i] += __shfl_xor(sm[i], off, 64);
    }
    __syncthreads();                       // finish min-reads before reuse
    if ((t & 63) == 0) {
        #pragma unroll
        for (int i = 0; i < 8; ++i) s_red[i][wid] = sm[i];
    }
    __syncthreads();
    #pragma unroll
    for (int i = 0; i < 8; ++i) {
        float4 r0 = *(const float4*)&s_red[i][0];
        float4 r1 = *(const float4*)&s_red[i][4];
        float rs = rcp_fast((r0.x + r0.y) + (r0.z + r0.w) + (r1.x + r1.y) + (r1.z + r1.w));
        float n  = p[i] * rs;
        attn[((size_t)b * SL + i0 + i) * SL + t] = n;   // coalesced
        s_p[i][t] = n;                                  // conflict-free
    }
    __syncthreads();

    // Phase 3: out[b,i0+ig,d] = sum_j p * inp.  ig = t>>6 (one i per wave), d-pair = t&63.
    const int d2 = t & 63, ig = t >> 6;
    const float2* inp2 = (const float2*)(inp + (size_t)b * SL * BD);
    float o0 = 0.f, o1 = 0.f;
    #pragma unroll 2
    for (int j4 = 0; j4 < SL / 4; ++j4) {
        float4 p4 = *(const float4*)&s_p[ig][j4 * 4];   // b128 broadcast per 4 j
        float2 x0 = inp2[(j4 * 4 + 0) * (BD / 2) + d2]; // coalesced 512B/wave
        float2 x1 = inp2[(j4 * 4 + 1) * (BD / 2) + d2];
        float2 x2 = inp2[(j4 * 4 + 2) * (BD / 2) + d2];
        float2 x3 = inp2[(j4 * 4 + 3) * (BD / 2) + d2];
        o0 = fmaf(p4.x, x0.x, o0);  o1 = fmaf(p4.x, x0.y, o1);
        o0 = fmaf(p4.y, x1.x, o0);  o1 = fmaf(p4.y, x1.y, o1);
        o0 = fmaf(p4.z, x2.x, o0);  o1 = fmaf(p4.z, x2.y, o1);
        o0 = fmaf(p4.w, x3.x, o0);  o1 = fmaf(p4.w, x3.y, o1);
    }
    float2* outp = (float2*)(out + ((size_t)b * SL + i0 + ig) * BD);
    outp[d2] = make_float2(o0, o1);        // coalesced
}

extern "C" void kernel_launch(void* const* d_in, const int* in_sizes, int n_in,
                              void* d_out, int out_size, void* d_ws, size_t ws_size,
                              hipStream_t stream) {
    const float* inp = (const float*)d_in[0];
    const float* Wu  = (const float*)d_in[1];
    const float* Ww  = (const float*)d_in[2];
    const float* Wv  = (const float*)d_in[3];

    float* out  = (float*)d_out;
    float* attn = out + (size_t)NB * SL * BD;   // out (B,L,D) then attn (B,L,L)

    float* ws  = (float*)d_ws;
    float* Equ = ws;                            // (B, D, L) exp(2*qu), transposed
    float* Ekw = Equ + (size_t)NB * BD * SL;    // (B, L, D) exp(2*kw)

    k_qk<<<NB * SL / 4, 256, 0, stream>>>(inp, Wu, Ww, Equ, Ekw);
    k_attn<<<NB * SL / 8, 512, 0, stream>>>(inp, Wv, Equ, Ekw, out, attn);
}

// Round 4
// 118.737 us; speedup vs baseline: 1.0192x; 1.0192x over previous
//
#include <hip/hip_runtime.h>

#define BD 128   // D
#define SL 512   // L
#define NB 4     // B

__device__ __forceinline__ float rcp_fast(float x) { return __builtin_amdgcn_rcpf(x); }

// K0: transpose Wu, Ww (row-major (out,in)) -> WT[k][o]. 64 blocks, trivial.
__global__ __launch_bounds__(256) void k_tr(const float* __restrict__ Wu,
                                            const float* __restrict__ Ww,
                                            float* __restrict__ WuT,
                                            float* __restrict__ WwT) {
    int idx = blockIdx.x * 256 + threadIdx.x;   // 0..16383
    int k = idx >> 7, o = idx & 127;
    WuT[idx] = Wu[o * BD + k];   // write coalesced; read strided (L2-absorbed, 64KB)
    WwT[idx] = Ww[o * BD + k];
}

// K1: qu = inp@Wu.T, kw = inp@Ww.T. 8 rows/block, 256 thr: t<128 -> qu col o, else kw.
// Writes Equ = exp(2qu) in PACKED layout [b][d>>2][l][d&3] (so k_attn loads float4 of
// 4 consecutive d per j), Ekw = exp(2kw) row-major (b,l,d).
__global__ __launch_bounds__(256) void k_qk(const float* __restrict__ inp,
                                            const float* __restrict__ WuT,
                                            const float* __restrict__ WwT,
                                            float* __restrict__ Equ,
                                            float* __restrict__ Ekw) {
    __shared__ float sx[8][BD];
    const int t = threadIdx.x, m = t >> 7, o = t & 127;
    const int r0 = blockIdx.x * 8;          // global row = b*SL + l
    const int b  = r0 >> 9;
    const int l0 = r0 & (SL - 1);

    #pragma unroll
    for (int h = 0; h < 4; ++h) {
        int id = h * 256 + t;               // 0..1023
        sx[id >> 7][id & 127] = inp[(size_t)r0 * BD + id];   // coalesced
    }
    __syncthreads();

    const float* WT = m ? WwT : WuT;        // WT[k][o], read coalesced + L2-hot
    float acc[8] = {0.f, 0.f, 0.f, 0.f, 0.f, 0.f, 0.f, 0.f};
    #pragma unroll 8
    for (int k = 0; k < BD; ++k) {
        float w = WT[k * BD + o];
        #pragma unroll
        for (int rr = 0; rr < 8; ++rr)
            acc[rr] = fmaf(sx[rr][k], w, acc[rr]);   // LDS broadcast
    }

    if (m == 0) {
        #pragma unroll
        for (int rr = 0; rr < 8; ++rr)      // packed scatter (1 MB total, negligible)
            Equ[(((size_t)b * 32 + (o >> 2)) * SL + (l0 + rr)) * 4 + (o & 3)] =
                __expf(2.f * acc[rr]);
    } else {
        #pragma unroll
        for (int rr = 0; rr < 8; ++rr)      // coalesced
            Ekw[(size_t)(r0 + rr) * BD + o] = __expf(2.f * acc[rr]);
    }
}

// K2: block = (b, 8 query rows i), 512 threads; thread t owns key column j=t.
// Phase 1: a[i] = sum_d wv/(1+Equ[d][j]*Ekw[i][d]) via packed float4 Equ loads
// (1 coalesced float4 = 4 d-values -> 32 rcp+64 fma per load; latency trivially hidden).
// Phase 2: softmax over j (score = C-2a, C cancels). Phase 3: out = attn @ inp.
__global__ __launch_bounds__(512) void k_attn(const float* __restrict__ inp,
                                              const float* __restrict__ Wv,
                                              const float* __restrict__ Equ,
                                              const float* __restrict__ Ekw,
                                              float* __restrict__ out,
                                              float* __restrict__ attn) {
    __shared__ float4 s_e0[BD];            // Ekw[i=0..3][d]
    __shared__ float4 s_e1[BD];            // Ekw[i=4..7][d]
    __shared__ float  s_wv[BD];
    __shared__ float  s_p[8][SL];          // normalized attn weights
    __shared__ float  s_red[8][8];         // [i][wave]

    const int t  = threadIdx.x;            // = j in phase 1
    const int b  = blockIdx.x >> 6;
    const int i0 = (blockIdx.x & 63) * 8;

    if (t < BD) {
        const float* ek = Ekw + ((size_t)b * SL + i0) * BD + t;   // coalesced per i
        s_e0[t] = make_float4(ek[0], ek[BD], ek[2 * BD], ek[3 * BD]);
        s_e1[t] = make_float4(ek[4 * BD], ek[5 * BD], ek[6 * BD], ek[7 * BD]);
        s_wv[t] = Wv[t];
    }
    __syncthreads();

    // Phase 1
    const float4* equ4 = (const float4*)(Equ + (size_t)b * BD * SL);  // [32][SL] float4
    float a[8] = {0.f, 0.f, 0.f, 0.f, 0.f, 0.f, 0.f, 0.f};
    #pragma unroll 2
    for (int c = 0; c < 32; ++c) {
        float4 q = equ4[c * SL + t];       // coalesced 1KB/wave, covers 4 d
        #pragma unroll
        for (int dd = 0; dd < 4; ++dd) {
            int   d  = c * 4 + dd;
            float qd = (dd == 0) ? q.x : (dd == 1) ? q.y : (dd == 2) ? q.z : q.w;
            float4 e0 = s_e0[d];           // wave-uniform b128 broadcast
            float4 e1 = s_e1[d];
            float  w  = s_wv[d];
            a[0] = fmaf(w, rcp_fast(fmaf(qd, e0.x, 1.f)), a[0]);
            a[1] = fmaf(w, rcp_fast(fmaf(qd, e0.y, 1.f)), a[1]);
            a[2] = fmaf(w, rcp_fast(fmaf(qd, e0.z, 1.f)), a[2]);
            a[3] = fmaf(w, rcp_fast(fmaf(qd, e0.w, 1.f)), a[3]);
            a[4] = fmaf(w, rcp_fast(fmaf(qd, e1.x, 1.f)), a[4]);
            a[5] = fmaf(w, rcp_fast(fmaf(qd, e1.y, 1.f)), a[5]);
            a[6] = fmaf(w, rcp_fast(fmaf(qd, e1.z, 1.f)), a[6]);
            a[7] = fmaf(w, rcp_fast(fmaf(qd, e1.w, 1.f)), a[7]);
        }
    }

    // Phase 2: softmax over j of score = -2a -> reduce MIN of a per row.
    const int wid = t >> 6;
    float mn[8];
    #pragma unroll
    for (int i = 0; i < 8; ++i) mn[i] = a[i];
    #pragma unroll
    for (int off = 32; off > 0; off >>= 1) {
        #pragma unroll
        for (int i = 0; i < 8; ++i) mn[i] = fminf(mn[i], __shfl_xor(mn[i], off, 64));
    }
    if ((t & 63) == 0) {
        #pragma unroll
        for (int i = 0; i < 8; ++i) s_red[i][wid] = mn[i];
    }
    __syncthreads();
    #pragma unroll
    for (int i = 0; i < 8; ++i) {
        float4 r0 = *(const float4*)&s_red[i][0];
        float4 r1 = *(const float4*)&s_red[i][4];
        mn[i] = fminf(fminf(fminf(r0.x, r0.y), fminf(r0.z, r0.w)),
                      fminf(fminf(r1.x, r1.y), fminf(r1.z, r1.w)));
    }

    float p[8], sm[8];
    #pragma unroll
    for (int i = 0; i < 8; ++i) { p[i] = __expf(-2.f * (a[i] - mn[i])); sm[i] = p[i]; }
    #pragma unroll
    for (int off = 32; off > 0; off >>= 1) {
        #pragma unroll
        for (int i = 0; i < 8; ++i) sm[i] += __shfl_xor(sm[i], off, 64);
    }
    __syncthreads();                       // finish min-reads before s_red reuse
    if ((t & 63) == 0) {
        #pragma unroll
        for (int i = 0; i < 8; ++i) s_red[i][wid] = sm[i];
    }
    __syncthreads();
    #pragma unroll
    for (int i = 0; i < 8; ++i) {
        float4 r0 = *(const float4*)&s_red[i][0];
        float4 r1 = *(const float4*)&s_red[i][4];
        float rs = rcp_fast((r0.x + r0.y) + (r0.z + r0.w) + (r1.x + r1.y) + (r1.z + r1.w));
        float n  = p[i] * rs;
        attn[((size_t)b * SL + i0 + i) * SL + t] = n;   // coalesced
        s_p[i][t] = n;
    }
    __syncthreads();

    // Phase 3: out[b,i0+ig,d] = sum_j p * inp.  ig = t>>6 (one i per wave), d-pair = t&63.
    const int d2 = t & 63, ig = t >> 6;
    const float2* inp2 = (const float2*)(inp + (size_t)b * SL * BD);
    float o0 = 0.f, o1 = 0.f;
    #pragma unroll 2
    for (int j4 = 0; j4 < SL / 4; ++j4) {
        float4 p4 = *(const float4*)&s_p[ig][j4 * 4];   // wave-uniform b128 broadcast
        float2 x0 = inp2[(j4 * 4 + 0) * (BD / 2) + d2]; // coalesced 512B/wave
        float2 x1 = inp2[(j4 * 4 + 1) * (BD / 2) + d2];
        float2 x2 = inp2[(j4 * 4 + 2) * (BD / 2) + d2];
        float2 x3 = inp2[(j4 * 4 + 3) * (BD / 2) + d2];
        o0 = fmaf(p4.x, x0.x, o0);  o1 = fmaf(p4.x, x0.y, o1);
        o0 = fmaf(p4.y, x1.x, o0);  o1 = fmaf(p4.y, x1.y, o1);
        o0 = fmaf(p4.z, x2.x, o0);  o1 = fmaf(p4.z, x2.y, o1);
        o0 = fmaf(p4.w, x3.x, o0);  o1 = fmaf(p4.w, x3.y, o1);
    }
    float2* outp = (float2*)(out + ((size_t)b * SL + i0 + ig) * BD);
    outp[d2] = make_float2(o0, o1);        // coalesced
}

extern "C" void kernel_launch(void* const* d_in, const int* in_sizes, int n_in,
                              void* d_out, int out_size, void* d_ws, size_t ws_size,
                              hipStream_t stream) {
    const float* inp = (const float*)d_in[0];
    const float* Wu  = (const float*)d_in[1];
    const float* Ww  = (const float*)d_in[2];
    const float* Wv  = (const float*)d_in[3];

    float* out  = (float*)d_out;
    float* attn = out + (size_t)NB * SL * BD;     // out (B,L,D) then attn (B,L,L)

    float* ws  = (float*)d_ws;
    float* Equ = ws;                              // (B, D/4, L, 4) packed exp(2*qu)
    float* Ekw = Equ + (size_t)NB * BD * SL;      // (B, L, D) exp(2*kw)
    float* WuT = Ekw + (size_t)NB * SL * BD;
    float* WwT = WuT + BD * BD;

    k_tr  <<<BD * BD / 256, 256, 0, stream>>>(Wu, Ww, WuT, WwT);
    k_qk  <<<NB * SL / 8, 256, 0, stream>>>(inp, WuT, WwT, Equ, Ekw);
    k_attn<<<NB * SL / 8, 512, 0, stream>>>(inp, Wv, Equ, Ekw, out, attn);
}

// Round 5
// 95.064 us; speedup vs baseline: 1.2730x; 1.2490x over previous
//
#include <hip/hip_runtime.h>

#define BD 128   // D
#define SL 512   // L
#define NB 4     // B

__device__ __forceinline__ float rcp_fast(float x) { return __builtin_amdgcn_rcpf(x); }

// K0: transpose Wu, Ww (row-major (out,in)) -> WT[k][o]. 64 blocks, trivial.
__global__ __launch_bounds__(256) void k_tr(const float* __restrict__ Wu,
                                            const float* __restrict__ Ww,
                                            float* __restrict__ WuT,
                                            float* __restrict__ WwT) {
    int idx = blockIdx.x * 256 + threadIdx.x;   // 0..16383
    int k = idx >> 7, o = idx & 127;
    WuT[idx] = Wu[o * BD + k];
    WwT[idx] = Ww[o * BD + k];
}

// K1: qu = inp@Wu.T, kw = inp@Ww.T. 4 rows/block, 512 blocks (2/CU, 8 waves/CU).
// t<128 -> qu col o, t>=128 -> kw col o. Equ packed [b][d>>2][l][d&3]; Ekw (b,l,d).
__global__ __launch_bounds__(256) void k_qk(const float* __restrict__ inp,
                                            const float* __restrict__ WuT,
                                            const float* __restrict__ WwT,
                                            float* __restrict__ Equ,
                                            float* __restrict__ Ekw) {
    __shared__ float sx[4][BD];
    const int t = threadIdx.x, m = t >> 7, o = t & 127;
    const int r0 = blockIdx.x * 4;          // global row = b*SL + l
    const int b  = r0 >> 9;
    const int l0 = r0 & (SL - 1);

    #pragma unroll
    for (int h = 0; h < 2; ++h) {
        int id = h * 256 + t;               // 0..511
        sx[id >> 7][id & 127] = inp[(size_t)r0 * BD + id];   // coalesced
    }
    __syncthreads();

    const float* WT = m ? WwT : WuT;        // WT[k][o], coalesced + L2-hot
    float acc[4] = {0.f, 0.f, 0.f, 0.f};
    #pragma unroll 8
    for (int k = 0; k < BD; ++k) {
        float w = WT[k * BD + o];           // 8 loads in flight via unroll
        #pragma unroll
        for (int rr = 0; rr < 4; ++rr)
            acc[rr] = fmaf(sx[rr][k], w, acc[rr]);   // LDS broadcast
    }

    if (m == 0) {
        #pragma unroll
        for (int rr = 0; rr < 4; ++rr)
            Equ[(((size_t)b * 32 + (o >> 2)) * SL + (l0 + rr)) * 4 + (o & 3)] =
                __expf(2.f * acc[rr]);
    } else {
        #pragma unroll
        for (int rr = 0; rr < 4; ++rr)
            Ekw[(size_t)(r0 + rr) * BD + o] = __expf(2.f * acc[rr]);
    }
}

// K2: block = (b, 8 query rows), 1024 threads (16 waves/CU = 4/SIMD).
// Phase 1 d-split: t<512 -> d 0..63, t>=512 -> d 64..127; j = t&511; 8 rcp chains.
// Phase 2: each d-half owns 4 rows of softmax. Phase 3: 4i x 4d register tile,
// x float4 from L2, p b128 from transposed s_pT, 16-way j-split + LDS reduce.
__global__ __launch_bounds__(1024, 4) void k_attn(const float* __restrict__ inp,
                                                  const float* __restrict__ Wv,
                                                  const float* __restrict__ Equ,
                                                  const float* __restrict__ Ekw,
                                                  float* __restrict__ out,
                                                  float* __restrict__ attn) {
    __shared__ float4 smem4[(SL * 8 + 15 * 8 * BD) / 4];   // 76 KB
    float* smem  = (float*)smem4;
    float* s_pT  = smem;                 // [SL][8] attn transposed
    float* ovl   = smem + SL * 8;        // overlay region (phase1/2, then s_fin)
    float4* s_e0 = (float4*)ovl;         // [BD] Ekw rows 0..3
    float4* s_e1 = ((float4*)ovl) + BD;  // [BD] Ekw rows 4..7
    float* s_wv  = ovl + 1024;           // [BD]
    float* s_ap  = ovl + 1152;           // [8][SL] partial a
    float* s_red = ovl + 5248;           // [2][4][8]
    float* s_fin = ovl;                  // [15][8][BD] phase-3 partials

    const int t  = threadIdx.x;
    const int b  = blockIdx.x >> 6;
    const int i0 = (blockIdx.x & 63) * 8;

    if (t < BD) {
        const float* ek = Ekw + ((size_t)b * SL + i0) * BD + t;
        s_e0[t] = make_float4(ek[0], ek[BD], ek[2 * BD], ek[3 * BD]);
        s_e1[t] = make_float4(ek[4 * BD], ek[5 * BD], ek[6 * BD], ek[7 * BD]);
        s_wv[t] = Wv[t];
    }
    __syncthreads();

    // ---- Phase 1: a[i] = sum_{d in half} wv/(1+Equ[d][j]*Ekw[i][d]) ----
    const int j = t & 511, dh = t >> 9;
    const float4* equ4 = (const float4*)(Equ + (size_t)b * BD * SL);
    float a[8] = {0.f, 0.f, 0.f, 0.f, 0.f, 0.f, 0.f, 0.f};
    #pragma unroll 4
    for (int cc = 0; cc < 16; ++cc) {
        int c = dh * 16 + cc;
        float4 q = equ4[c * SL + j];       // coalesced 1KB/wave, 4 d-values
        float qs[4] = {q.x, q.y, q.z, q.w};
        #pragma unroll
        for (int dd = 0; dd < 4; ++dd) {
            int d = c * 4 + dd;
            float4 e0 = s_e0[d];           // wave-uniform b128 broadcast
            float4 e1 = s_e1[d];
            float  w  = s_wv[d];
            float  qd = qs[dd];
            a[0] = fmaf(w, rcp_fast(fmaf(qd, e0.x, 1.f)), a[0]);
            a[1] = fmaf(w, rcp_fast(fmaf(qd, e0.y, 1.f)), a[1]);
            a[2] = fmaf(w, rcp_fast(fmaf(qd, e0.z, 1.f)), a[2]);
            a[3] = fmaf(w, rcp_fast(fmaf(qd, e0.w, 1.f)), a[3]);
            a[4] = fmaf(w, rcp_fast(fmaf(qd, e1.x, 1.f)), a[4]);
            a[5] = fmaf(w, rcp_fast(fmaf(qd, e1.y, 1.f)), a[5]);
            a[6] = fmaf(w, rcp_fast(fmaf(qd, e1.z, 1.f)), a[6]);
            a[7] = fmaf(w, rcp_fast(fmaf(qd, e1.w, 1.f)), a[7]);
        }
    }

    // Combine d-halves: dh0 posts rows 4..7, dh1 posts rows 0..3; each finalizes its own 4.
    const int ro = dh * 4;                 // rows this thread owns from here on
    const int wo = 4 - ro;                 // rows it posts
    #pragma unroll
    for (int ii = 0; ii < 4; ++ii) s_ap[(wo + ii) * SL + j] = a[wo + ii];
    __syncthreads();
    float af[4];
    #pragma unroll
    for (int ii = 0; ii < 4; ++ii) af[ii] = a[ro + ii] + s_ap[(ro + ii) * SL + j];

    // ---- Phase 2: softmax over j of score = -2*af (reduce MIN of af) ----
    const int w8 = j >> 6;
    float mn[4];
    #pragma unroll
    for (int ii = 0; ii < 4; ++ii) mn[ii] = af[ii];
    #pragma unroll
    for (int off = 32; off > 0; off >>= 1) {
        #pragma unroll
        for (int ii = 0; ii < 4; ++ii) mn[ii] = fminf(mn[ii], __shfl_xor(mn[ii], off, 64));
    }
    if ((j & 63) == 0) {
        #pragma unroll
        for (int ii = 0; ii < 4; ++ii) s_red[(dh * 4 + ii) * 8 + w8] = mn[ii];
    }
    __syncthreads();
    #pragma unroll
    for (int ii = 0; ii < 4; ++ii) {
        float4 r0 = *(const float4*)&s_red[(dh * 4 + ii) * 8];
        float4 r1 = *(const float4*)&s_red[(dh * 4 + ii) * 8 + 4];
        mn[ii] = fminf(fminf(fminf(r0.x, r0.y), fminf(r0.z, r0.w)),
                       fminf(fminf(r1.x, r1.y), fminf(r1.z, r1.w)));
    }

    float p[4], sm[4];
    #pragma unroll
    for (int ii = 0; ii < 4; ++ii) { p[ii] = __expf(-2.f * (af[ii] - mn[ii])); sm[ii] = p[ii]; }
    #pragma unroll
    for (int off = 32; off > 0; off >>= 1) {
        #pragma unroll
        for (int ii = 0; ii < 4; ++ii) sm[ii] += __shfl_xor(sm[ii], off, 64);
    }
    __syncthreads();                       // finish min-reads before s_red reuse
    if ((j & 63) == 0) {
        #pragma unroll
        for (int ii = 0; ii < 4; ++ii) s_red[(dh * 4 + ii) * 8 + w8] = sm[ii];
    }
    __syncthreads();
    float n[4];
    #pragma unroll
    for (int ii = 0; ii < 4; ++ii) {
        float4 r0 = *(const float4*)&s_red[(dh * 4 + ii) * 8];
        float4 r1 = *(const float4*)&s_red[(dh * 4 + ii) * 8 + 4];
        float rs = rcp_fast((r0.x + r0.y) + (r0.z + r0.w) + (r1.x + r1.y) + (r1.z + r1.w));
        n[ii] = p[ii] * rs;
        attn[((size_t)b * SL + i0 + ro + ii) * SL + j] = n[ii];   // coalesced
    }
    ((float4*)s_pT)[j * 2 + dh] = make_float4(n[0], n[1], n[2], n[3]);
    __syncthreads();

    // ---- Phase 3: out = attn @ inp; 4i x 4d register tile, 16-way j-split ----
    const int g   = t >> 6;                // j-group (one wave): j = g*32 .. g*32+31
    const int ln  = t & 63;
    const int dq  = ln & 31;               // d-quad
    const int ig4 = ln >> 5;               // 0: rows 0..3, 1: rows 4..7
    const float4* inp4 = (const float4*)(inp + (size_t)b * SL * BD);
    float4 acc[4];
    #pragma unroll
    for (int ii = 0; ii < 4; ++ii) acc[ii] = make_float4(0.f, 0.f, 0.f, 0.f);
    #pragma unroll 4
    for (int jj = 0; jj < 32; ++jj) {
        int jr = g * 32 + jj;
        float4 x  = inp4[jr * 32 + dq];                      // L2-hit b128
        float4 pp = *(const float4*)&s_pT[jr * 8 + ig4 * 4]; // 2-addr LDS b128
        acc[0].x = fmaf(pp.x, x.x, acc[0].x); acc[0].y = fmaf(pp.x, x.y, acc[0].y);
        acc[0].z = fmaf(pp.x, x.z, acc[0].z); acc[0].w = fmaf(pp.x, x.w, acc[0].w);
        acc[1].x = fmaf(pp.y, x.x, acc[1].x); acc[1].y = fmaf(pp.y, x.y, acc[1].y);
        acc[1].z = fmaf(pp.y, x.z, acc[1].z); acc[1].w = fmaf(pp.y, x.w, acc[1].w);
        acc[2].x = fmaf(pp.z, x.x, acc[2].x); acc[2].y = fmaf(pp.z, x.y, acc[2].y);
        acc[2].z = fmaf(pp.z, x.z, acc[2].z); acc[2].w = fmaf(pp.z, x.w, acc[2].w);
        acc[3].x = fmaf(pp.w, x.x, acc[3].x); acc[3].y = fmaf(pp.w, x.y, acc[3].y);
        acc[3].z = fmaf(pp.w, x.z, acc[3].z); acc[3].w = fmaf(pp.w, x.w, acc[3].w);
    }
    __syncthreads();                       // ovl region now free for s_fin
    if (g) {
        #pragma unroll
        for (int ii = 0; ii < 4; ++ii)
            *(float4*)&s_fin[((g - 1) * 8 + ig4 * 4 + ii) * BD + dq * 4] = acc[ii];
    }
    __syncthreads();
    if (g == 0) {
        #pragma unroll
        for (int r = 0; r < 15; ++r) {
            #pragma unroll
            for (int ii = 0; ii < 4; ++ii) {
                float4 v = *(const float4*)&s_fin[(r * 8 + ig4 * 4 + ii) * BD + dq * 4];
                acc[ii].x += v.x; acc[ii].y += v.y; acc[ii].z += v.z; acc[ii].w += v.w;
            }
        }
        #pragma unroll
        for (int ii = 0; ii < 4; ++ii)
            *(float4*)&out[((size_t)b * SL + i0 + ig4 * 4 + ii) * BD + dq * 4] = acc[ii];
    }
}

extern "C" void kernel_launch(void* const* d_in, const int* in_sizes, int n_in,
                              void* d_out, int out_size, void* d_ws, size_t ws_size,
                              hipStream_t stream) {
    const float* inp = (const float*)d_in[0];
    const float* Wu  = (const float*)d_in[1];
    const float* Ww  = (const float*)d_in[2];
    const float* Wv  = (const float*)d_in[3];

    float* out  = (float*)d_out;
    float* attn = out + (size_t)NB * SL * BD;     // out (B,L,D) then attn (B,L,L)

    float* ws  = (float*)d_ws;
    float* Equ = ws;                              // (B, D/4, L, 4) packed exp(2*qu)
    float* Ekw = Equ + (size_t)NB * BD * SL;      // (B, L, D) exp(2*kw)
    float* WuT = Ekw + (size_t)NB * SL * BD;
    float* WwT = WuT + BD * BD;

    k_tr  <<<BD * BD / 256, 256, 0, stream>>>(Wu, Ww, WuT, WwT);
    k_qk  <<<NB * SL / 4, 256, 0, stream>>>(inp, WuT, WwT, Equ, Ekw);
    k_attn<<<NB * SL / 8, 1024, 0, stream>>>(inp, Wv, Equ, Ekw, out, attn);
}